// Round 16
// baseline (11657.616 us; speedup 1.0000x reference)
//
#include <hip/hip_runtime.h>
#include <stdint.h>
#include <stddef.h>

// ACT-LSTM, B=32 T=512 IN=50 H=512 OUT=66, MAX_PONDER=10, EPS=0.01, fp32.
// Round 16: CONTROL — byte-for-byte resubmission of the round-11 kernel
// (last known pass, 11,532 us). Rounds 12-15 all failed with bit-identical
// absmax, including R15 which differed from R11 only by a value-preserving
// register preload; this run isolates the binary as the only variable.
// 8 independent groups x 32 blocks (256 blocks, 1/CU). Group G owns batches
// [4G,4G+4) with a private timeline -- NO global sync. Per phase: one step for
// 4 batches (4x2048x512 GEMV). Block r owns 16 j (all 4 gates = 64 cols).
// h-exchange = 8 KB/group at the MALL (sc0 sc1); each WAVE polls just its 8
// producer flags and stages its own 2 KB k-slice -> wave-local pipeline.
// gAcc linearity trick retained (fresh step needs no GEMM).

#define NBLK 256

// ---------------- ws layout (float offsets) ----------------
// wh   : [0, 8388608)            512*32*512  (32 MB)
// hbuf : [8388608, 8421376)      8 groups x 2 pp x 2048  ([k][4b] packing)
// bar  : [8421376, 8421888)      flags[256] (group G = [32G,32G+32))
// Wp   : [8421888, 9470464)      W_hh repacked [r][k4][c][kl]  (4 MB)
// W_iT : [9470464, 9574912)      51*2048     W_ih repacked [k][j*4+g]
// W_oT : [9574912, 9608704)      512*66      W_out transposed [k][o]
#define WS_NEED_BYTES 38434816ull

__device__ __forceinline__ float sigmf(float v) { return 1.0f / (1.0f + expf(-v)); }

// LLC-coherent (cross-XCD) stores: bypass L1+L2 (sc0 sc1).
__device__ __forceinline__ void store_llc(float* p, float v) {
  asm volatile("global_store_dword %0, %1, off sc0 sc1" :: "v"(p), "v"(v) : "memory");
}
__device__ __forceinline__ void store_llc_u(unsigned* p, unsigned v) {
  asm volatile("global_store_dword %0, %1, off sc0 sc1" :: "v"(p), "v"(v) : "memory");
}

#if defined(__has_builtin)
#if __has_builtin(__builtin_amdgcn_global_load_lds)
#define HAVE_GLLDS 1
#endif
#endif

// LLC-coherent global->LDS DMA, 16 B/lane. aux=0x11 = SC0|SC1.
__device__ __forceinline__ void stage_instr(const float* gp, float* lp) {
#ifdef HAVE_GLLDS
  __builtin_amdgcn_global_load_lds((const __attribute__((address_space(1))) unsigned int*)gp,
                                   (__attribute__((address_space(3))) unsigned int*)lp,
                                   16, 0, 0x11);
#else
  float4 tmp;
  asm volatile("global_load_dwordx4 %0, %1, off sc0 sc1" : "=v"(tmp) : "v"(gp) : "memory");
  asm volatile("s_waitcnt vmcnt(0)" ::: "memory");
  *(float4*)(lp + (threadIdx.x & 63) * 4) = tmp;
#endif
}

// ------------------------------------------------------------------
// prep: repack weights + zero flags.
// Wp[((r*128+k4)*64+c)*4+kl] = W_hh[((c&3)*512 + 16r + (c>>2))*512 + 4k4+kl]
__global__ void prep_k(const float* __restrict__ W_ih, const float* __restrict__ W_hh,
                       const float* __restrict__ W_out,
                       float* __restrict__ Wp, float* __restrict__ W_iT,
                       float* __restrict__ W_oT, unsigned* __restrict__ bar) {
  int idx = blockIdx.x * 256 + threadIdx.x;
  if (idx < 1048576) {
    int kl = idx & 3, c = (idx >> 2) & 63, k4 = (idx >> 8) & 127, r = idx >> 15;
    int row = (c & 3) * 512 + 16 * r + (c >> 2);
    Wp[idx] = W_hh[(size_t)row * 512 + 4 * k4 + kl];
  }
  int i2 = idx - 1048576;
  if (i2 >= 0 && i2 < 104448) {
    int col = i2 & 2047, k = i2 >> 11;
    int g = col & 3, j = col >> 2;
    W_iT[i2] = W_ih[(size_t)((g << 9) + j) * 51 + k];
  }
  int i3 = idx - 1153024;
  if (i3 >= 0 && i3 < 33792) {
    int k = i3 / 66, o = i3 - k * 66;
    W_oT[i3] = W_out[(size_t)o * 512 + k];
  }
  int i4 = idx - 1186816;
  if (i4 >= 0 && i4 < 256) bar[i4] = 0u;
}

// ------------------------------------------------------------------
// persistent ACT-LSTM: 256 blocks x 256 threads; group gid=bid>>5 (batches
// 4gid..4gid+3), rank r=bid&31 owns j in [16r,16r+16).
// (c,b)-role: c=tid&63 (col: g=c&3, jj=c>>2), batch=w=tid>>6. GEMV: thread
// computes col c x 4 batches over k-slice [128w,128w+128).
// Owner lane (tid<64): jj=tid>>2, bo=tid&3 owns (batch 4gid+bo, j=16r+jj);
// its h2 slot is hbG + pp*2048 + 64r + tid (contiguous across lanes).
// Decision lanes tid<4 (batch=tid).
__global__ void __launch_bounds__(256)
act_main(const float* __restrict__ x, const float* __restrict__ bvec,
         const float* __restrict__ W_halt, const float* __restrict__ b_halt,
         const float* __restrict__ Wp, const float* __restrict__ W_iT,
         float* __restrict__ hbuf, unsigned* __restrict__ bar,
         float* __restrict__ wh, float* __restrict__ p_out) {
  __shared__ float hst[2048];        // staged h [k][4b], 8 KB (wave-private 2KB regions)
  __shared__ float pacc[1024];       // GEMV partials [s][c][4b]
  __shared__ float xg2[256];         // final gate pre-acts [c][4b]
  __shared__ float hps[256];         // halt partials
  __shared__ float S_p[4];
  __shared__ int S_flag[1];

  const int tid = threadIdx.x, bid = blockIdx.x;
  const int gid = bid >> 5, r = bid & 31;
  const int c = tid & 63, w = tid >> 6, lane = tid & 63;
  const int jj = tid >> 2, bo = tid & 3;          // owner mapping (tid<64)
  const int ch = lane >> 2, b2 = lane & 3;        // halt-partial mapping
  unsigned* flags = bar + gid * 32;
  float* hbG = hbuf + gid * 4096;

  const float bh = b_halt[0];
  const int cg = 64 * r + c;                       // W_iT column for (r,c)
  const float bs = bvec[(c & 3) * 512 + 16 * r + (c >> 2)];
  const float wfc = W_iT[50 * 2048 + cg];

  // (c,batch=w) state
  float gAcc = 0.f, gxc, gxn = 0.f;
  {  // x-projection for t=0, batch 4gid+w
    gxc = bs;
    const float* xr = x + (size_t)(gid * 4 + w) * 512 * 50;
    for (int k = 0; k < 50; ++k) gxc = fmaf(xr[k], W_iT[k * 2048 + cg], gxc);
  }
  // owner state (tid<64)
  float cS = 0.f, hprev = 0.f, acc_h = 0.f, acc_c = 0.f;
  // decision state (tid<4)
  float cum = 0.f, nupd = 0.f, rem = 0.f;
  int mydone = 0;

  int t = 0, n = 0, first = 1;
  unsigned ph = 0;
  __syncthreads();

  while (true) {
    float val, cin = 0.f;
    if (first) {
      // phase 0: fresh step (t=0,n=0), h=0 -> gemm=0, gAcc=0
      val = gxc + wfc;
      first = 0;
    } else {
      // ---- per-wave poll: the 8 producers of this wave's k-slice ----
      {
        const unsigned* fp = flags + w * 8 + (lane & 7);
        while (true) {
          unsigned fv;
          asm volatile("global_load_dword %0, %1, off sc0 sc1" : "=v"(fv) : "v"(fp) : "memory");
          asm volatile("s_waitcnt vmcnt(0)" ::: "memory");
          if (__ballot((lane < 8) ? (fv >= ph) : 1) == ~0ull) break;
          __builtin_amdgcn_s_sleep(1);
        }
      }
      // ---- stage own 2 KB (k in [128w,+128), [k][4b]) ----
      {
        const float* gp = hbG + ((ph & 1u) ^ 1u) * 2048 + w * 512 + lane * 4;
        float* lp = hst + w * 512;
        stage_instr(gp, lp); stage_instr(gp + 256, lp + 256);
      }
      // under the DMA: x-projection for t+1 (once per timestep)
      if (n == 0) {
        const int tn = (t + 1 > 511) ? 511 : t + 1;
        gxn = bs;
        const float* xr = x + ((size_t)(gid * 4 + w) * 512 + tn) * 50;
        for (int k = 0; k < 50; ++k) gxn = fmaf(xr[k], W_iT[k * 2048 + cg], gxn);
      }
      asm volatile("s_waitcnt vmcnt(0)" ::: "memory");

      // ---- GEMV slice: col c, 4 batches, k in [128w,+128) ----
      {
        const float* wb = Wp + (size_t)r * 32768 + w * 8192 + c * 4;
        const float* hb = hst + w * 512;
        float a0 = 0.f, a1 = 0.f, a2 = 0.f, a3 = 0.f;
        #pragma unroll 8
        for (int i = 0; i < 32; ++i) {
          const float4 wv = *(const float4*)(wb + i * 256);   // 1 KB/wave, coalesced
          const float4 h0 = *(const float4*)(hb + i * 16);    // wave-uniform broadcast
          const float4 h1 = *(const float4*)(hb + i * 16 + 4);
          const float4 h2v = *(const float4*)(hb + i * 16 + 8);
          const float4 h3 = *(const float4*)(hb + i * 16 + 12);
          a0 = fmaf(wv.x, h0.x, a0); a1 = fmaf(wv.x, h0.y, a1);
          a2 = fmaf(wv.x, h0.z, a2); a3 = fmaf(wv.x, h0.w, a3);
          a0 = fmaf(wv.y, h1.x, a0); a1 = fmaf(wv.y, h1.y, a1);
          a2 = fmaf(wv.y, h1.z, a2); a3 = fmaf(wv.y, h1.w, a3);
          a0 = fmaf(wv.z, h2v.x, a0); a1 = fmaf(wv.z, h2v.y, a1);
          a2 = fmaf(wv.z, h2v.z, a2); a3 = fmaf(wv.z, h2v.w, a3);
          a0 = fmaf(wv.w, h3.x, a0); a1 = fmaf(wv.w, h3.y, a1);
          a2 = fmaf(wv.w, h3.z, a2); a3 = fmaf(wv.w, h3.w, a3);
        }
        float4 pv; pv.x = a0; pv.y = a1; pv.z = a2; pv.w = a3;
        *(float4*)(pacc + w * 256 + c * 4) = pv;   // lanes contiguous
      }
      // ---- halt partial on own slice: k = 128w + ch + 16i ----
      {
        float hp = 0.f;
        #pragma unroll
        for (int i = 0; i < 8; ++i) {
          const int k = 128 * w + ch + 16 * i;
          hp = fmaf(hst[k * 4 + b2], W_halt[k], hp);
        }
        hps[tid] = hp;     // partial for batch lane&3
      }
      __syncthreads();   // sync_c

      // (c,w): reduce own gate over the 4 k-slices
      const float g = pacc[c * 4 + w] + pacc[256 + c * 4 + w] +
                      pacc[512 + c * 4 + w] + pacc[768 + c * 4 + w];
      // wave 0: ACT decision for the 4 batches
      if (tid < 64) {
        int vote = 1;
        if (tid < 4) {
          float d = 0.f;
          for (int m = 0; m < 64; ++m) d += hps[m * 4 + tid];
          const float halt = sigmf(d + bh);
          const int done = mydone;
          const int halted = ((cum + halt) > 0.99f) || (n == 9);
          S_p[tid] = done ? 0.f : (halted ? (1.f - cum) : halt);
          nupd += done ? 0.f : 1.f;
          rem += (done || !halted) ? 0.f : (1.f - cum);
          cum += done ? 0.f : halt;
          mydone = done | halted;
          vote = mydone;
        }
        const unsigned long long bal = __ballot(vote);
        if (tid == 0) S_flag[0] = (bal == ~0ull) ? 1 : 0;
      }
      __syncthreads();   // sync_d

      const int alldone = S_flag[0];
      const float p = S_p[w];
      gAcc = fmaf(p, g, gAcc);
      if (tid < 64) {    // owner accumulate (weighted h,c of staged step)
        const float po = S_p[bo];
        acc_h = fmaf(po, hprev, acc_h);
        acc_c = fmaf(po, cS, acc_c);
      }
      if (alldone) {     // timestep t ends; fresh step of t+1 this phase
        if (tid < 64) {
          wh[(size_t)t * 16384 + (size_t)(gid * 4 + bo) * 512 + 16 * r + jj] = acc_h;
          cin = acc_c;
          acc_h = 0.f; acc_c = 0.f;
        }
        if (r == 0 && tid < 4)
          p_out[(size_t)(gid * 4 + tid) * 512 + t] = nupd + rem;
        if (tid < 4) { cum = 0.f; nupd = 0.f; rem = 0.f; mydone = 0; }
        val = gxn + wfc + gAcc;      // fresh gates: no GEMM (linearity)
        gAcc = 0.f; gxc = gxn;
        t += 1; n = 0;
        if (t == 512) break;         // uniform within block & group
      } else {
        if (tid < 64) cin = cS;
        val = gxc + g;
        n += 1;
      }
    }

    xg2[c * 4 + w] = val;
    __syncthreads();   // sync_e
    if (tid < 64) {    // owner (jj,bo): cell step; publish h2 (coalesced); flag
      const float gi = xg2[16 * jj + 0 + bo];
      const float gf = xg2[16 * jj + 4 + bo];
      const float gg = xg2[16 * jj + 8 + bo];
      const float go = xg2[16 * jj + 12 + bo];
      const float c_new = sigmf(gf) * cin + sigmf(gi) * tanhf(gg);
      const float h_new = sigmf(go) * tanhf(c_new);
      cS = c_new; hprev = h_new;
      store_llc(hbG + (ph & 1u) * 2048 + 64 * r + tid, h_new);
      asm volatile("s_waitcnt vmcnt(0)" ::: "memory");
      if (tid == 0) store_llc_u(&flags[r], ph + 1u);
    }
    ph += 1;
  }
}

// ------------------------------------------------------------------
// epilogue: out[b,t,:] = seg-softmax(wh[t,b,:] @ W_out^T + b_out)
__global__ void __launch_bounds__(256)
epi_k(const float* __restrict__ wh, const float* __restrict__ W_oT,
      const float* __restrict__ b_out, float* __restrict__ out) {
  __shared__ float hl[4][512];
  __shared__ float yl[4][66];
  const int tid = threadIdx.x, pair = tid >> 6, lane = tid & 63;
  const int bt = blockIdx.x * 4 + pair;
  const int b = bt >> 9, t = bt & 511;
  const float* hsrc = wh + (size_t)t * 16384 + (size_t)b * 512;
  *(float4*)&hl[pair][lane * 8] = *(const float4*)(hsrc + lane * 8);
  *(float4*)&hl[pair][lane * 8 + 4] = *(const float4*)(hsrc + lane * 8 + 4);
  __syncthreads();
  if (lane < 33) {
    const int o = lane * 2;
    float y0 = b_out[o], y1 = b_out[o + 1];
    const float* hp_ = hl[pair];
    #pragma unroll 8
    for (int k = 0; k < 512; ++k) {
      const float h = hp_[k];
      const float2 wv = *(const float2*)(W_oT + k * 66 + o);
      y0 = fmaf(h, wv.x, y0);
      y1 = fmaf(h, wv.y, y1);
    }
    yl[pair][o] = y0; yl[pair][o + 1] = y1;
  }
  __syncthreads();
  if (tid < 24) {
    const int pr = tid / 6, g = tid - pr * 6;
    const int bt2 = blockIdx.x * 4 + pr;
    const float* yp = &yl[pr][g * 11];
    float m = yp[0];
    for (int u = 1; u < 11; ++u) m = fmaxf(m, yp[u]);
    float e[11], ssum = 0.f;
    for (int u = 0; u < 11; ++u) { e[u] = expf(yp[u] - m); ssum += e[u]; }
    const float inv = 1.0f / ssum;
    float* op = out + (size_t)bt2 * 66 + g * 11;
    for (int u = 0; u < 11; ++u) op[u] = e[u] * inv;
  }
}

// ------------------------------------------------------------------
extern "C" void kernel_launch(void* const* d_in, const int* in_sizes, int n_in,
                              void* d_out, int out_size, void* d_ws, size_t ws_size,
                              hipStream_t stream) {
  (void)in_sizes; (void)n_in; (void)out_size;
  const float* x      = (const float*)d_in[0];
  const float* W_ih   = (const float*)d_in[1];
  const float* W_hh   = (const float*)d_in[2];
  const float* bvec   = (const float*)d_in[3];
  const float* W_out  = (const float*)d_in[4];
  const float* b_out  = (const float*)d_in[5];
  const float* W_halt = (const float*)d_in[6];
  const float* b_halt = (const float*)d_in[7];
  float* out = (float*)d_out;
  float* ws  = (float*)d_ws;

  if (ws_size < (size_t)WS_NEED_BYTES) return;  // visible failure if ws too small

  float* wh     = ws;
  float* hbuf   = ws + 8388608;
  unsigned* bar = (unsigned*)(ws + 8421376);
  float* Wp     = ws + 8421888;
  float* W_iT   = ws + 9470464;
  float* W_oT   = ws + 9574912;
  float* p_out  = out + 1081344;  // B*T*OUT

  hipLaunchKernelGGL(prep_k, dim3(4638), dim3(256), 0, stream,
                     W_ih, W_hh, W_out, Wp, W_iT, W_oT, bar);

  void* args[10];
  args[0] = (void*)&x;      args[1] = (void*)&bvec;  args[2] = (void*)&W_halt;
  args[3] = (void*)&b_halt; args[4] = (void*)&Wp;    args[5] = (void*)&W_iT;
  args[6] = (void*)&hbuf;   args[7] = (void*)&bar;   args[8] = (void*)&wh;
  args[9] = (void*)&p_out;
  (void)hipLaunchCooperativeKernel((void*)act_main, dim3(NBLK), dim3(256), args, 0, stream);

  hipLaunchKernelGGL(epi_k, dim3(4096), dim3(256), 0, stream, wh, W_oT, b_out, out);
}